// Round 1
// baseline (24.759 us; speedup 1.0000x reference)
//
#include <hip/hip_runtime.h>

// GraphAttentionPooling: B=8, N=6144, F=512, p=3 (N % p == 0, no ragged tail).
// Per group of 3 rows: logits = x @ w + b, att = softmax over the 3 rows,
// out[f] = sum_k att[k] * x[k][f].  Output [B, steps, F, 1] flat = group*F + f.
//
// Memory-bound: ~100.7 MB read + 32 MB write -> ~21 us at 6.3 TB/s.
// One wave (64 lanes) per group; each lane owns floats {lane*4..+3} and
// {256+lane*4..+3} of each 512-float row (two float4 loads per row, fully
// coalesced: 64 lanes x 16 B = 1024 B per instruction).

#define GAP_F 512
#define GAP_P 3

__global__ __launch_bounds__(256) void gap_kernel(
    const float* __restrict__ x,   // [ngroups, 3, 512]
    const float* __restrict__ w,   // [512]
    const float* __restrict__ bptr,// [1]
    float* __restrict__ out,       // [ngroups, 512]
    int ngroups)
{
    const int gwave = (int)((blockIdx.x * blockDim.x + threadIdx.x) >> 6);
    const int lane  = threadIdx.x & 63;
    if (gwave >= ngroups) return;

    const float* gx = x + (size_t)gwave * (GAP_P * GAP_F);

    // weight fragments (L1/L2 resident after first wave)
    const float4 w0 = *(const float4*)(w + lane * 4);
    const float4 w1 = *(const float4*)(w + 256 + lane * 4);

    // three rows, two float4 each
    const float4 x00 = *(const float4*)(gx + 0 * GAP_F + lane * 4);
    const float4 x01 = *(const float4*)(gx + 0 * GAP_F + 256 + lane * 4);
    const float4 x10 = *(const float4*)(gx + 1 * GAP_F + lane * 4);
    const float4 x11 = *(const float4*)(gx + 1 * GAP_F + 256 + lane * 4);
    const float4 x20 = *(const float4*)(gx + 2 * GAP_F + lane * 4);
    const float4 x21 = *(const float4*)(gx + 2 * GAP_F + 256 + lane * 4);

    // per-lane dot partials
    float d0 = x00.x * w0.x + x00.y * w0.y + x00.z * w0.z + x00.w * w0.w
             + x01.x * w1.x + x01.y * w1.y + x01.z * w1.z + x01.w * w1.w;
    float d1 = x10.x * w0.x + x10.y * w0.y + x10.z * w0.z + x10.w * w0.w
             + x11.x * w1.x + x11.y * w1.y + x11.z * w1.z + x11.w * w1.w;
    float d2 = x20.x * w0.x + x20.y * w0.y + x20.z * w0.z + x20.w * w0.w
             + x21.x * w1.x + x21.y * w1.y + x21.z * w1.z + x21.w * w1.w;

    // butterfly reduce across the 64-lane wave (every lane ends with full sum)
    #pragma unroll
    for (int off = 32; off >= 1; off >>= 1) {
        d0 += __shfl_xor(d0, off, 64);
        d1 += __shfl_xor(d1, off, 64);
        d2 += __shfl_xor(d2, off, 64);
    }

    const float b = *bptr;   // shift-invariant under softmax, kept for fidelity
    const float l0 = d0 + b, l1 = d1 + b, l2 = d2 + b;
    const float m  = fmaxf(fmaxf(l0, l1), l2);
    const float e0 = expf(l0 - m), e1 = expf(l1 - m), e2 = expf(l2 - m);
    const float inv = 1.0f / (e0 + e1 + e2);
    const float a0 = e0 * inv, a1 = e1 * inv, a2 = e2 * inv;

    float4 o0, o1;
    o0.x = a0 * x00.x + a1 * x10.x + a2 * x20.x;
    o0.y = a0 * x00.y + a1 * x10.y + a2 * x20.y;
    o0.z = a0 * x00.z + a1 * x10.z + a2 * x20.z;
    o0.w = a0 * x00.w + a1 * x10.w + a2 * x20.w;
    o1.x = a0 * x01.x + a1 * x11.x + a2 * x21.x;
    o1.y = a0 * x01.y + a1 * x11.y + a2 * x21.y;
    o1.z = a0 * x01.z + a1 * x11.z + a2 * x21.z;
    o1.w = a0 * x01.w + a1 * x11.w + a2 * x21.w;

    float* go = out + (size_t)gwave * GAP_F;
    *(float4*)(go + lane * 4)       = o0;
    *(float4*)(go + 256 + lane * 4) = o1;
}

extern "C" void kernel_launch(void* const* d_in, const int* in_sizes, int n_in,
                              void* d_out, int out_size, void* d_ws, size_t ws_size,
                              hipStream_t stream) {
    const float* x = (const float*)d_in[0];   // [B, N, F] fp32
    const float* w = (const float*)d_in[1];   // [F, 1]
    const float* b = (const float*)d_in[2];   // [1]
    float* out = (float*)d_out;               // [B, steps, F, 1]

    const int ngroups = in_sizes[0] / (GAP_P * GAP_F);  // B * steps = 16384

    const int waves_per_block = 4;                       // 256 threads
    const int nblocks = (ngroups + waves_per_block - 1) / waves_per_block;
    gap_kernel<<<nblocks, 256, 0, stream>>>(x, w, b, out, ngroups);
}

// Round 3
// 24.567 us; speedup vs baseline: 1.0078x; 1.0078x over previous
//
#include <hip/hip_runtime.h>

// GraphAttentionPooling: B=8, N=6144, F=512, p=3 (N % p == 0, no ragged tail).
// Per group of 3 rows: logits = x @ w + b, att = softmax over the 3 rows,
// out[f] = sum_k att[k] * x[k][f].  Output [B, steps, F, 1] flat = group*F + f.
//
// Memory-bound: ~100.7 MB read + 33.6 MB write -> ~21.3 us at 6.29 TB/s copy
// ceiling. R1 measured 24.76 us (5.42 TB/s). This round: nontemporal stores
// for the output stream (never re-read by the kernel) to keep the 32 MB write
// stream from write-allocating into L2 against the 100 MB read stream.
// (R2 compile fix: __builtin_nontemporal_store needs a native clang vector
// type, not HIP's float4 class.)
//
// One wave (64 lanes) per group; each lane owns floats {lane*4..+3} and
// {256+lane*4..+3} of each 512-float row (two float4 loads per row, fully
// coalesced: 64 lanes x 16 B = 1 KiB per instruction).

#define GAP_F 512
#define GAP_P 3

typedef float nativef4 __attribute__((ext_vector_type(4)));

__global__ __launch_bounds__(256) void gap_kernel(
    const float* __restrict__ x,   // [ngroups, 3, 512]
    const float* __restrict__ w,   // [512]
    const float* __restrict__ bptr,// [1]
    float* __restrict__ out,       // [ngroups, 512]
    int ngroups)
{
    const int gwave = (int)((blockIdx.x * blockDim.x + threadIdx.x) >> 6);
    const int lane  = threadIdx.x & 63;
    if (gwave >= ngroups) return;

    const float* gx = x + (size_t)gwave * (GAP_P * GAP_F);

    // weight fragments (L1/L2 resident after first wave)
    const float4 w0 = *(const float4*)(w + lane * 4);
    const float4 w1 = *(const float4*)(w + 256 + lane * 4);

    // three rows, two float4 each
    const float4 x00 = *(const float4*)(gx + 0 * GAP_F + lane * 4);
    const float4 x01 = *(const float4*)(gx + 0 * GAP_F + 256 + lane * 4);
    const float4 x10 = *(const float4*)(gx + 1 * GAP_F + lane * 4);
    const float4 x11 = *(const float4*)(gx + 1 * GAP_F + 256 + lane * 4);
    const float4 x20 = *(const float4*)(gx + 2 * GAP_F + lane * 4);
    const float4 x21 = *(const float4*)(gx + 2 * GAP_F + 256 + lane * 4);

    // per-lane dot partials
    float d0 = x00.x * w0.x + x00.y * w0.y + x00.z * w0.z + x00.w * w0.w
             + x01.x * w1.x + x01.y * w1.y + x01.z * w1.z + x01.w * w1.w;
    float d1 = x10.x * w0.x + x10.y * w0.y + x10.z * w0.z + x10.w * w0.w
             + x11.x * w1.x + x11.y * w1.y + x11.z * w1.z + x11.w * w1.w;
    float d2 = x20.x * w0.x + x20.y * w0.y + x20.z * w0.z + x20.w * w0.w
             + x21.x * w1.x + x21.y * w1.y + x21.z * w1.z + x21.w * w1.w;

    // butterfly reduce across the 64-lane wave (every lane ends with full sum)
    #pragma unroll
    for (int off = 32; off >= 1; off >>= 1) {
        d0 += __shfl_xor(d0, off, 64);
        d1 += __shfl_xor(d1, off, 64);
        d2 += __shfl_xor(d2, off, 64);
    }

    const float b = *bptr;   // shift-invariant under softmax, kept for fidelity
    const float l0 = d0 + b, l1 = d1 + b, l2 = d2 + b;
    const float m  = fmaxf(fmaxf(l0, l1), l2);
    const float e0 = expf(l0 - m), e1 = expf(l1 - m), e2 = expf(l2 - m);
    const float inv = 1.0f / (e0 + e1 + e2);
    const float a0 = e0 * inv, a1 = e1 * inv, a2 = e2 * inv;

    nativef4 o0, o1;
    o0.x = a0 * x00.x + a1 * x10.x + a2 * x20.x;
    o0.y = a0 * x00.y + a1 * x10.y + a2 * x20.y;
    o0.z = a0 * x00.z + a1 * x10.z + a2 * x20.z;
    o0.w = a0 * x00.w + a1 * x10.w + a2 * x20.w;
    o1.x = a0 * x01.x + a1 * x11.x + a2 * x21.x;
    o1.y = a0 * x01.y + a1 * x11.y + a2 * x21.y;
    o1.z = a0 * x01.z + a1 * x11.z + a2 * x21.z;
    o1.w = a0 * x01.w + a1 * x11.w + a2 * x21.w;

    float* go = out + (size_t)gwave * GAP_F;
    // nontemporal: output is write-once, never re-read by this kernel --
    // keep the write stream from thrashing L2 against the read stream.
    __builtin_nontemporal_store(o0, (nativef4*)(go + lane * 4));
    __builtin_nontemporal_store(o1, (nativef4*)(go + 256 + lane * 4));
}

extern "C" void kernel_launch(void* const* d_in, const int* in_sizes, int n_in,
                              void* d_out, int out_size, void* d_ws, size_t ws_size,
                              hipStream_t stream) {
    const float* x = (const float*)d_in[0];   // [B, N, F] fp32
    const float* w = (const float*)d_in[1];   // [F, 1]
    const float* b = (const float*)d_in[2];   // [1]
    float* out = (float*)d_out;               // [B, steps, F, 1]

    const int ngroups = in_sizes[0] / (GAP_P * GAP_F);  // B * steps = 16384

    const int waves_per_block = 4;                       // 256 threads
    const int nblocks = (ngroups + waves_per_block - 1) / waves_per_block;
    gap_kernel<<<nblocks, 256, 0, stream>>>(x, w, b, out, ngroups);
}